// Round 4
// baseline (427.767 us; speedup 1.0000x reference)
//
#include <hip/hip_runtime.h>

typedef unsigned short u16;
typedef unsigned int u32;
typedef unsigned long long u64;
typedef __attribute__((ext_vector_type(8))) short bf16x8;
typedef __attribute__((ext_vector_type(4))) short bf16x4;
typedef __attribute__((ext_vector_type(4))) float f32x4;
typedef __attribute__((ext_vector_type(2))) unsigned int u32x2;

#define AS1(p) ((const __attribute__((address_space(1))) void*)(p))
#define AS3(p) ((__attribute__((address_space(3))) void*)(p))

__device__ __forceinline__ u16 f2bf(float f) {   // RNE
    u32 u = __float_as_uint(f);
    u += 0x7fff + ((u >> 16) & 1);
    return (u16)(u >> 16);
}
// pack two floats to packed bf16x2 (round-half-up)
__device__ __forceinline__ u32 pack2bf(float lo, float hi) {
    u32 a = __float_as_uint(lo) + 0x8000u;
    u32 b = __float_as_uint(hi) + 0x8000u;
    return __builtin_amdgcn_perm(b, a, 0x07060302);   // {b[3],b[2],a[3],a[2]}
}
// single-instruction packed f32->bf16x2 (RNE) — no builtin on gfx950, asm per guide
__device__ __forceinline__ u32 cvtpk(float lo, float hi) {
    u32 r;
    asm("v_cvt_pk_bf16_f32 %0, %1, %2" : "=v"(r) : "v"(lo), "v"(hi));
    return r;
}

__device__ __forceinline__ void async16(const u16* g, u16* l) {
    __builtin_amdgcn_global_load_lds(AS1(g), AS3(l), 16, 0, 0);
}

// ---------------- fp32 -> bf16 conversion ----------------
__global__ __launch_bounds__(256) void cvt_kernel(const float* __restrict__ src,
                                                  u16* __restrict__ dst, int n) {
    int idx = (blockIdx.x * 256 + threadIdx.x) * 8;
    if (idx >= n) return;
    float4 a = *(const float4*)(src + idx);
    float4 b = *(const float4*)(src + idx + 4);
    uint4 o;
    o.x = (u32)f2bf(a.x) | ((u32)f2bf(a.y) << 16);
    o.y = (u32)f2bf(a.z) | ((u32)f2bf(a.w) << 16);
    o.z = (u32)f2bf(b.x) | ((u32)f2bf(b.y) << 16);
    o.w = (u32)f2bf(b.z) | ((u32)f2bf(b.w) << 16);
    *(uint4*)(dst + idx) = o;
}

__global__ __launch_bounds__(256) void cvt4_kernel(
    const float* __restrict__ s0, const float* __restrict__ s1,
    const float* __restrict__ s2, const float* __restrict__ s3,
    u16* __restrict__ d0, u16* __restrict__ d1,
    u16* __restrict__ d2, u16* __restrict__ d3) {
    const float* s; u16* d;
    switch (blockIdx.y) {
        case 0:  s = s0; d = d0; break;
        case 1:  s = s1; d = d1; break;
        case 2:  s = s2; d = d2; break;
        default: s = s3; d = d3; break;
    }
    int idx = (blockIdx.x * 256 + threadIdx.x) * 8;
    float4 a = *(const float4*)(s + idx);
    float4 b = *(const float4*)(s + idx + 4);
    uint4 o;
    o.x = (u32)f2bf(a.x) | ((u32)f2bf(a.y) << 16);
    o.y = (u32)f2bf(a.z) | ((u32)f2bf(a.w) << 16);
    o.z = (u32)f2bf(b.x) | ((u32)f2bf(b.y) << 16);
    o.w = (u32)f2bf(b.z) | ((u32)f2bf(b.w) << 16);
    *(uint4*)(d + idx) = o;
}

// ---------------- GEMM: C[m][o] = sum_k A[m][k]*W[o][k] + bias[o] ----------------
// XCD-swizzled: XCD g owns y-chunk [g*8, g*8+8) for all x,z so A panels are
// fetched into exactly one XCD's L2 (dispatch round-robins blocks over 8 XCDs).
// NOTE: no aggressive launch_bounds — (256,4) caps VGPR at 128 and spills the
// 64-VGPR accumulator to scratch (R4: 2.6 GB HBM traffic, 4x regression).
// mode 0: z=0 -> Q bf16 (nh,s,d) pre-scaled by 0.125*log2e; z=1 -> K bf16 (nh,s,d);
//         z=2 -> V^T bf16 (nh,d,s) — all coalesced via LDS transpose
// mode 1: fp32 row-major (m,o) output
__global__ __launch_bounds__(256, 2) void gemm_bt(
    const u16* __restrict__ A,
    const u16* __restrict__ Wa, const u16* __restrict__ Wb, const u16* __restrict__ Wc,
    const float* __restrict__ ba, const float* __restrict__ bb, const float* __restrict__ bc,
    void* oa, void* ob_, void* oc, int mode)
{
    constexpr int K = 1024;
    __shared__ u16 smem[128 * 132];   // k-loop: At=smem[0..4095], Wt=smem[4096..8191]
    u16* At = smem;
    u16* Wt = smem + 4096;

    const int tid = threadIdx.x;
    const int lane = tid & 63, wv = tid >> 6;
    const int l15 = lane & 15, quad = lane >> 4;
    const int wr = wv >> 1, wc = wv & 1;

    // XCD-aware swizzle (grid is 8 x 64 x z; dispatch order = linear L)
    const int L = blockIdx.x + (blockIdx.y << 3) + (blockIdx.z << 9);
    const int g = L & 7;          // XCD (assumes round-robin dispatch)
    const int j = L >> 3;
    const int z = j >> 6;         // 0..2 (or 0)
    const int r = j & 63;
    const int m0 = ((g << 3) + (r & 7)) * 128;   // y-chunk per XCD
    const int n0 = (r >> 3) * 128;

    const u16* W = (z == 0) ? Wa : ((z == 1) ? Wb : Wc);
    const float* bs = (z == 0) ? ba : ((z == 1) ? bb : bc);
    void* out = (z == 0) ? oa : ((z == 1) ? ob_ : oc);
    const bool swap_ = (mode == 1) || (z < 2);   // swapped: tile row = o, col = m

    f32x4 acc[4][4];
#pragma unroll
    for (int i = 0; i < 4; ++i)
#pragma unroll
        for (int j2 = 0; j2 < 4; ++j2) acc[i][j2] = (f32x4)0.f;

    const int call0 = wv * 2;
    for (int kk = 0; kk < K; kk += 32) {
#pragma unroll
        for (int jj = 0; jj < 2; ++jj) {
            int c = (call0 + jj) * 64 + lane;
            int row = c >> 2;
            int ko = ((c & 3) ^ (row & 3)) * 8;   // XOR swizzle of k-chunks per row
            async16(A + (size_t)(m0 + row) * K + kk + ko, &At[(call0 + jj) * 512 + lane * 8]);
            async16(W + (size_t)(n0 + row) * K + kk + ko, &Wt[(call0 + jj) * 512 + lane * 8]);
        }
        __syncthreads();

        bf16x8 af[4], wf[4];
#pragma unroll
        for (int t = 0; t < 4; ++t) {
            int rowa = wr * 64 + t * 16 + l15;
            af[t] = *(const bf16x8*)&At[rowa * 32 + ((quad ^ (rowa & 3)) * 8)];
            int rowb = wc * 64 + t * 16 + l15;
            wf[t] = *(const bf16x8*)&Wt[rowb * 32 + ((quad ^ (rowb & 3)) * 8)];
        }
        if (swap_) {
#pragma unroll
            for (int rt = 0; rt < 4; ++rt)
#pragma unroll
                for (int ct = 0; ct < 4; ++ct)
                    acc[rt][ct] = __builtin_amdgcn_mfma_f32_16x16x32_bf16(wf[ct], af[rt], acc[rt][ct], 0, 0, 0);
        } else {
#pragma unroll
            for (int rt = 0; rt < 4; ++rt)
#pragma unroll
                for (int ct = 0; ct < 4; ++ct)
                    acc[rt][ct] = __builtin_amdgcn_mfma_f32_16x16x32_bf16(af[rt], wf[ct], acc[rt][ct], 0, 0, 0);
        }
        __syncthreads();
    }

    if (mode == 1) {
        // swapped: row = o (quad*4+r), col = m (l15); pack float4 over o — coalesced fp32
#pragma unroll
        for (int rt = 0; rt < 4; ++rt)
#pragma unroll
            for (int ct = 0; ct < 4; ++ct) {
                int m_ = m0 + wr * 64 + rt * 16 + l15;
                int ob = n0 + wc * 64 + ct * 16 + quad * 4;
                float4 b4 = *(const float4*)&bs[ob];
                float4 v;
                v.x = acc[rt][ct][0] + b4.x;
                v.y = acc[rt][ct][1] + b4.y;
                v.z = acc[rt][ct][2] + b4.z;
                v.w = acc[rt][ct][3] + b4.w;
                *(float4*)((float*)out + (size_t)m_ * 1024 + ob) = v;
            }
        return;
    }

    const int n = m0 >> 11, s0 = m0 & 2047;
    if (z < 2) {
        // tile -> LDS T[m][o] (132 stride), then coalesced (nh,s,d) streams
        const float qs = (z == 0) ? 0.18033688011112042f : 1.0f;  // 0.125*log2(e)
#pragma unroll
        for (int rt = 0; rt < 4; ++rt)
#pragma unroll
            for (int ct = 0; ct < 4; ++ct) {
                int ml = wr * 64 + rt * 16 + l15;
                int ol = wc * 64 + ct * 16 + quad * 4;
                float4 b4 = *(const float4*)&bs[n0 + ol];
                float v0 = (acc[rt][ct][0] + b4.x) * qs;
                float v1 = (acc[rt][ct][1] + b4.y) * qs;
                float v2 = (acc[rt][ct][2] + b4.z) * qs;
                float v3 = (acc[rt][ct][3] + b4.w) * qs;
                u32x2 pv = { pack2bf(v0, v1), pack2bf(v2, v3) };
                *(u32x2*)&smem[ml * 132 + ol] = pv;
            }
        __syncthreads();
        const int h0 = n0 >> 6;
#pragma unroll
        for (int p = 0; p < 8; ++p) {
            int hh = p >> 2, qq = p & 3;
            int m = qq * 32 + (tid >> 3), d = (tid & 7) * 8;
            bf16x8 vv = *(const bf16x8*)&smem[m * 132 + hh * 64 + d];
            u16* dst = (u16*)out + ((size_t)((n * 16 + h0 + hh) * 2048 + s0 + m)) * 64 + d;
            *(bf16x8*)dst = vv;
        }
    } else {
        // V^T: tile -> LDS T[o][m], then coalesced (nh,d,s) rows
#pragma unroll
        for (int rt = 0; rt < 4; ++rt)
#pragma unroll
            for (int ct = 0; ct < 4; ++ct) {
                int ol = wc * 64 + ct * 16 + l15;
                int ml = wr * 64 + rt * 16 + quad * 4;
                float b = bs[n0 + ol];
                float v0 = acc[rt][ct][0] + b;
                float v1 = acc[rt][ct][1] + b;
                float v2 = acc[rt][ct][2] + b;
                float v3 = acc[rt][ct][3] + b;
                u32x2 pv = { pack2bf(v0, v1), pack2bf(v2, v3) };
                *(u32x2*)&smem[ol * 132 + ml] = pv;
            }
        __syncthreads();
#pragma unroll
        for (int p = 0; p < 8; ++p) {
            int o = p * 16 + (tid >> 4), ms = (tid & 15) * 8;
            bf16x8 vv = *(const bf16x8*)&smem[o * 132 + ms];
            int og = n0 + o;
            int h = og >> 6, d = og & 63;
            u16* dst = (u16*)out + ((size_t)((n * 16 + h) * 64 + d)) * 2048 + s0 + ms;
            *(bf16x8*)dst = vv;
        }
    }
}

// ---------------- flash attention ----------------
// Q bf16 (nh,s,d) PRE-SCALED by 0.125*log2e; K bf16 (nh,s,d); VT bf16 (nh,d,s).
// S^T = K.Q^T; fixed-max softmax (scores bounded: exp2 sums < 2^20, fp32-safe).
// R3: QBLK=64/wave (LDS per work halved) -> 87us, MfmaUtil 32, VALU 44.
// R4: ONE-TILE SOFTWARE PIPELINE. The per-wave chain QK->softmax->PV was
// strictly serial (softmax ~650 issue-cyc VALU+TRANS vs QK ~310 MFMA-pipe-cyc,
// neither pipe >50%). Now iter it computes QK(it) into sacc_cur while
// softmax+PV FINISH tile it-1 (no data dependency): the exp2/cvtpk/permlane
// stream executes on VALU/TRANS while the MFMA pipe chews QK, dovetailed
// per-jt so sacc_prev dies as sacc_cur fills (peak ~235 VGPR, fits (256,2)).
// Buffers: K/V[2]; stage tile it+1 into slot (it+1)&1 after PV(it-1) -- prior
// content (tile it-1) has K read last iter, V read this iter pre-barrier.
__global__ __launch_bounds__(256, 2) void attn_kernel(
    const u16* __restrict__ Q, const u16* __restrict__ K_,
    const u16* __restrict__ VT, const int* __restrict__ mask,
    u16* __restrict__ Y)
{
    constexpr int S = 2048, DK = 64, STR = 72;
    __shared__ u16 Kt[2][64 * STR];
    __shared__ u16 Vt[2][64 * STR];

    const int tid = threadIdx.x;
    const int lane = tid & 63, w = tid >> 6;
    const int l15 = lane & 15, quad = lane >> 4;

    // Bijective XCD swizzle (512 blocks % 8 == 0): XCD g gets vb in
    // [g*64, g*64+64) = 8 whole heads -> K/V live-set per XCD ~= 4MB = one L2.
    const int L = blockIdx.x + (blockIdx.y << 3);
    const int vb = (L & 7) * 64 + (L >> 3);
    const int nh = vb >> 3;
    const int n = nh >> 4, h = nh & 15;
    const int qbase = (vb & 7) * 256;

    const u16* Qh = Q + (size_t)nh * S * DK;
    const u16* Kh = K_ + (size_t)nh * S * DK;
    const u16* Vh = VT + (size_t)nh * DK * S;   // row d, stride S

    bf16x8 qf[4][2];
#pragma unroll
    for (int nt = 0; nt < 4; ++nt)
#pragma unroll
        for (int st = 0; st < 2; ++st)
            qf[nt][st] = *(const bf16x8*)(Qh + (size_t)(qbase + w * 64 + nt * 16 + l15) * DK + st * 32 + quad * 8);

    f32x4 o[4][4];   // [dt][nt]
#pragma unroll
    for (int dt = 0; dt < 4; ++dt)
#pragma unroll
        for (int nt = 0; nt < 4; ++nt) o[dt][nt] = (f32x4)0.f;
    float lsum[4] = {0.f, 0.f, 0.f, 0.f};

    const int r0 = tid >> 3, c8 = (tid & 7) * 8;

    // per-tile "fully unmasked" bitmap (one ballot per tile, once)
    u32 bm = 0;
    for (int t = 0; t < 32; ++t) {
        int mv = mask[n * S + t * 64 + lane];
        if (__ballot(mv != 0) == ~0ull) bm |= (1u << t);
    }

    // prologue: tiles 0,1 -> bufs 0,1
#pragma unroll
    for (int t = 0; t < 2; ++t) {
        bf16x8 k0 = *(const bf16x8*)(Kh + (size_t)(t * 64 + r0) * 64 + c8);
        bf16x8 k1 = *(const bf16x8*)(Kh + (size_t)(t * 64 + r0 + 32) * 64 + c8);
        bf16x8 v0 = *(const bf16x8*)(Vh + (size_t)r0 * S + t * 64 + c8);
        bf16x8 v1 = *(const bf16x8*)(Vh + (size_t)(r0 + 32) * S + t * 64 + c8);
        *(bf16x8*)&Kt[t][r0 * STR + c8] = k0;
        *(bf16x8*)&Kt[t][(r0 + 32) * STR + c8] = k1;
        *(bf16x8*)&Vt[t][r0 * STR + c8] = v0;
        *(bf16x8*)&Vt[t][(r0 + 32) * STR + c8] = v1;
    }
    __syncthreads();

    const f32x4 zf = (f32x4)0.f;
    f32x4 X[4][4], Yc[4][4];   // two score-tile buffers [jt][nt]

    // QK(0) -> X
    __builtin_amdgcn_s_setprio(1);
#pragma unroll
    for (int jt = 0; jt < 4; ++jt) {
        bf16x8 kf0 = *(const bf16x8*)&Kt[0][(jt * 16 + l15) * STR + quad * 8];
        bf16x8 kf1 = *(const bf16x8*)&Kt[0][(jt * 16 + l15) * STR + 32 + quad * 8];
#pragma unroll
        for (int nt = 0; nt < 4; ++nt) {
            X[jt][nt] = __builtin_amdgcn_mfma_f32_16x16x32_bf16(kf0, qf[nt][0], zf, 0, 0, 0);
            X[jt][nt] = __builtin_amdgcn_mfma_f32_16x16x32_bf16(kf1, qf[nt][1], X[jt][nt], 0, 0, 0);
        }
    }
    __builtin_amdgcn_s_setprio(0);

    // BODY(SP,SC,ITC): QK(ITC)->SC dovetailed with softmax of SP (tile ITC-1),
    // then PV(ITC-1), then stage tile ITC+1 into buf[(ITC+1)&1].
#define BODY(SP, SC, ITC) do {                                                           \
    const int cur_ = (ITC) & 1, prv_ = cur_ ^ 1;                                         \
    const int tm_ = (ITC) - 1;                                                           \
    const int kkn_ = (((ITC) + 1) << 6) & (S - 1);                                       \
    bf16x8 rk0_ = *(const bf16x8*)(Kh + (size_t)(kkn_ + r0) * 64 + c8);                  \
    bf16x8 rk1_ = *(const bf16x8*)(Kh + (size_t)(kkn_ + r0 + 32) * 64 + c8);             \
    if (!((bm >> tm_) & 1)) {   /* rare: tile has masked keys */                         \
        for (int jt = 0; jt < 4; ++jt)                                                   \
            for (int rr = 0; rr < 4; ++rr) {                                             \
                int mv = mask[n * S + tm_ * 64 + jt * 16 + quad * 4 + rr];               \
                for (int nt = 0; nt < 4; ++nt)                                           \
                    if (mv == 0) SP[jt][nt][rr] = -1e30f;                                \
            }                                                                            \
    }                                                                                    \
    u32 pkx_[4][4], pky_[4][4];   /* [nt][jt] */                                         \
    float ps_[4] = {0.f, 0.f, 0.f, 0.f};                                                 \
    __builtin_amdgcn_s_setprio(1);                                                       \
    _Pragma("unroll")                                                                    \
    for (int jt = 0; jt < 4; ++jt) {                                                     \
        bf16x8 kf0 = *(const bf16x8*)&Kt[cur_][(jt * 16 + l15) * STR + quad * 8];        \
        bf16x8 kf1 = *(const bf16x8*)&Kt[cur_][(jt * 16 + l15) * STR + 32 + quad * 8];   \
        _Pragma("unroll")                                                                \
        for (int nt = 0; nt < 4; ++nt) {                                                 \
            SC[jt][nt] = __builtin_amdgcn_mfma_f32_16x16x32_bf16(kf0, qf[nt][0], zf, 0, 0, 0); \
            SC[jt][nt] = __builtin_amdgcn_mfma_f32_16x16x32_bf16(kf1, qf[nt][1], SC[jt][nt], 0, 0, 0); \
        }                                                                                \
        _Pragma("unroll")                                                                \
        for (int nt = 0; nt < 4; ++nt) {   /* softmax(SP[jt]) overlaps SC MFMAs */       \
            float e0 = __builtin_amdgcn_exp2f(SP[jt][nt][0]);                            \
            float e1 = __builtin_amdgcn_exp2f(SP[jt][nt][1]);                            \
            float e2 = __builtin_amdgcn_exp2f(SP[jt][nt][2]);                            \
            float e3 = __builtin_amdgcn_exp2f(SP[jt][nt][3]);                            \
            ps_[nt] += (e0 + e1) + (e2 + e3);                                            \
            pkx_[nt][jt] = cvtpk(e0, e1);                                                \
            pky_[nt][jt] = cvtpk(e2, e3);                                                \
        }                                                                                \
    }                                                                                    \
    __builtin_amdgcn_s_setprio(0);                                                       \
    bf16x8 pb_[4][2];                                                                    \
    _Pragma("unroll")                                                                    \
    for (int nt = 0; nt < 4; ++nt) {                                                     \
        lsum[nt] += ps_[nt];                                                             \
        _Pragma("unroll")                                                                \
        for (int kt = 0; kt < 2; ++kt) {                                                 \
            auto rX_ = __builtin_amdgcn_permlane32_swap(pkx_[nt][2 * kt], pkx_[nt][2 * kt + 1], false, false); \
            auto rY_ = __builtin_amdgcn_permlane32_swap(pky_[nt][2 * kt], pky_[nt][2 * kt + 1], false, false); \
            auto sX_ = __builtin_amdgcn_permlane16_swap(rX_[0], rX_[1], false, false);   \
            auto sY_ = __builtin_amdgcn_permlane16_swap(rY_[0], rY_[1], false, false);   \
            union { u32 u[4]; bf16x8 v; } pu_;                                           \
            pu_.u[0] = sX_[0]; pu_.u[1] = sY_[0]; pu_.u[2] = sX_[1]; pu_.u[3] = sY_[1];  \
            pb_[nt][kt] = pu_.v;                                                         \
        }                                                                                \
    }                                                                                    \
    bf16x8 rv0_ = *(const bf16x8*)(Vh + (size_t)r0 * S + kkn_ + c8);                     \
    bf16x8 rv1_ = *(const bf16x8*)(Vh + (size_t)(r0 + 32) * S + kkn_ + c8);              \
    __builtin_amdgcn_s_setprio(1);                                                       \
    _Pragma("unroll")                                                                    \
    for (int kt = 0; kt < 2; ++kt) {                                                     \
        _Pragma("unroll")                                                                \
        for (int dt = 0; dt < 4; ++dt) {                                                 \
            bf16x8 vf_ = *(const bf16x8*)&Vt[prv_][(dt * 16 + l15) * STR + kt * 32 + quad * 8]; \
            _Pragma("unroll")                                                            \
            for (int nt = 0; nt < 4; ++nt)                                               \
                o[dt][nt] = __builtin_amdgcn_mfma_f32_16x16x32_bf16(vf_, pb_[nt][kt], o[dt][nt], 0, 0, 0); \
        }                                                                                \
    }                                                                                    \
    __builtin_amdgcn_s_setprio(0);                                                       \
    __syncthreads();   /* all waves done reading buf[prv_] (K last iter, V above) */     \
    *(bf16x8*)&Kt[prv_][r0 * STR + c8] = rk0_;                                           \
    *(bf16x8*)&Kt[prv_][(r0 + 32) * STR + c8] = rk1_;                                    \
    *(bf16x8*)&Vt[prv_][r0 * STR + c8] = rv0_;                                           \
    *(bf16x8*)&Vt[prv_][(r0 + 32) * STR + c8] = rv1_;                                    \
    __syncthreads();   /* publish tile ITC+1 */                                          \
} while (0)

    for (int b = 1; b < 31; b += 2) {
        BODY(X, Yc, b);
        BODY(Yc, X, b + 1);
    }
    BODY(X, Yc, 31);
    // degenerate body: finishes tile 31 from Yc; its QK(32) result (X) is dead -> DCE'd
    BODY(Yc, X, 32);
#undef BODY

    // ---- epilogue ----
#pragma unroll
    for (int nt = 0; nt < 4; ++nt) {
        float ls = lsum[nt];
        ls += __shfl_xor(ls, 16);
        ls += __shfl_xor(ls, 32);
        float rl = (ls > 0.f) ? 1.f / ls : 0.f;
        int qi = qbase + w * 64 + nt * 16 + l15;
#pragma unroll
        for (int dt = 0; dt < 4; ++dt) {
            u32x2 pv = { pack2bf(o[dt][nt][0] * rl, o[dt][nt][1] * rl),
                         pack2bf(o[dt][nt][2] * rl, o[dt][nt][3] * rl) };
            size_t base = ((size_t)(n * 2048 + qi)) * 1024 + h * 64 + dt * 16 + quad * 4;
            *(u32x2*)(Y + base) = pv;
        }
    }
}

// ---------------- host ----------------
extern "C" void kernel_launch(void* const* d_in, const int* in_sizes, int n_in,
                              void* d_out, int out_size, void* d_ws, size_t ws_size,
                              hipStream_t stream) {
    const float* x  = (const float*)d_in[0];
    const int* mask = (const int*)d_in[1];
    const float* Wq = (const float*)d_in[2];
    const float* bq = (const float*)d_in[3];
    const float* Wk = (const float*)d_in[4];
    const float* bk = (const float*)d_in[5];
    const float* Wv = (const float*)d_in[6];
    const float* bv = (const float*)d_in[7];
    const float* Wp = (const float*)d_in[8];
    const float* bp = (const float*)d_in[9];

    char* ws = (char*)d_ws;
    u16* xb  = (u16*)(ws);
    u16* wqb = (u16*)(ws + (16u << 20));
    u16* wkb = (u16*)(ws + (18u << 20));
    u16* wvb = (u16*)(ws + (20u << 20));
    u16* wpb = (u16*)(ws + (22u << 20));
    u16* Qb  = (u16*)(ws + (24u << 20));
    u16* Kb  = (u16*)(ws + (40u << 20));
    u16* Vb  = (u16*)(ws + (56u << 20));   // V^T (nh, d, s)
    u16* Yb  = (u16*)(ws + (72u << 20));

    cvt_kernel<<<4096, 256, 0, stream>>>(x, xb, 8388608);
    cvt4_kernel<<<dim3(512, 4), 256, 0, stream>>>(Wq, Wk, Wv, Wp, wqb, wkb, wvb, wpb);

    gemm_bt<<<dim3(8, 64, 3), 256, 0, stream>>>(xb, wqb, wkb, wvb, bq, bk, bv,
                                                (void*)Qb, (void*)Kb, (void*)Vb, 0);

    attn_kernel<<<dim3(8, 64), 256, 0, stream>>>(Qb, Kb, Vb, mask, Yb);

    gemm_bt<<<dim3(8, 64, 1), 256, 0, stream>>>(Yb, wpb, wpb, wpb, bp, bp, bp,
                                                d_out, d_out, d_out, 1);
}

// Round 5
// 268.691 us; speedup vs baseline: 1.5920x; 1.5920x over previous
//
#include <hip/hip_runtime.h>

typedef unsigned short u16;
typedef unsigned int u32;
typedef unsigned long long u64;
typedef __attribute__((ext_vector_type(8))) short bf16x8;
typedef __attribute__((ext_vector_type(4))) short bf16x4;
typedef __attribute__((ext_vector_type(4))) float f32x4;
typedef __attribute__((ext_vector_type(2))) unsigned int u32x2;

#define AS1(p) ((const __attribute__((address_space(1))) void*)(p))
#define AS3(p) ((__attribute__((address_space(3))) void*)(p))

__device__ __forceinline__ u16 f2bf(float f) {   // RNE
    u32 u = __float_as_uint(f);
    u += 0x7fff + ((u >> 16) & 1);
    return (u16)(u >> 16);
}
// pack two floats to packed bf16x2 (round-half-up)
__device__ __forceinline__ u32 pack2bf(float lo, float hi) {
    u32 a = __float_as_uint(lo) + 0x8000u;
    u32 b = __float_as_uint(hi) + 0x8000u;
    return __builtin_amdgcn_perm(b, a, 0x07060302);   // {b[3],b[2],a[3],a[2]}
}
// single-instruction packed f32->bf16x2 (RNE) — no builtin on gfx950, asm per guide
__device__ __forceinline__ u32 cvtpk(float lo, float hi) {
    u32 r;
    asm("v_cvt_pk_bf16_f32 %0, %1, %2" : "=v"(r) : "v"(lo), "v"(hi));
    return r;
}

__device__ __forceinline__ void async16(const u16* g, u16* l) {
    __builtin_amdgcn_global_load_lds(AS1(g), AS3(l), 16, 0, 0);
}

// ---------------- fp32 -> bf16 conversion ----------------
__global__ __launch_bounds__(256) void cvt_kernel(const float* __restrict__ src,
                                                  u16* __restrict__ dst, int n) {
    int idx = (blockIdx.x * 256 + threadIdx.x) * 8;
    if (idx >= n) return;
    float4 a = *(const float4*)(src + idx);
    float4 b = *(const float4*)(src + idx + 4);
    uint4 o;
    o.x = (u32)f2bf(a.x) | ((u32)f2bf(a.y) << 16);
    o.y = (u32)f2bf(a.z) | ((u32)f2bf(a.w) << 16);
    o.z = (u32)f2bf(b.x) | ((u32)f2bf(b.y) << 16);
    o.w = (u32)f2bf(b.z) | ((u32)f2bf(b.w) << 16);
    *(uint4*)(dst + idx) = o;
}

__global__ __launch_bounds__(256) void cvt4_kernel(
    const float* __restrict__ s0, const float* __restrict__ s1,
    const float* __restrict__ s2, const float* __restrict__ s3,
    u16* __restrict__ d0, u16* __restrict__ d1,
    u16* __restrict__ d2, u16* __restrict__ d3) {
    const float* s; u16* d;
    switch (blockIdx.y) {
        case 0:  s = s0; d = d0; break;
        case 1:  s = s1; d = d1; break;
        case 2:  s = s2; d = d2; break;
        default: s = s3; d = d3; break;
    }
    int idx = (blockIdx.x * 256 + threadIdx.x) * 8;
    float4 a = *(const float4*)(s + idx);
    float4 b = *(const float4*)(s + idx + 4);
    uint4 o;
    o.x = (u32)f2bf(a.x) | ((u32)f2bf(a.y) << 16);
    o.y = (u32)f2bf(a.z) | ((u32)f2bf(a.w) << 16);
    o.z = (u32)f2bf(b.x) | ((u32)f2bf(b.y) << 16);
    o.w = (u32)f2bf(b.z) | ((u32)f2bf(b.w) << 16);
    *(uint4*)(d + idx) = o;
}

// ---------------- GEMM: C[m][o] = sum_k A[m][k]*W[o][k] + bias[o] ----------------
// XCD-swizzled (R0). R5: T3 "minimum 2-phase" K-loop — the old loop was
// stage -> __syncthreads (vmcnt(0) drain!) -> compute: global->LDS latency
// exposed on every one of the 32 K-steps. Now At/Wt are double-buffered inside
// the same 33.8KB smem (4x8KB), STAGE(t+1) issues BEFORE compute(t), and each
// step ends with raw s_waitcnt vmcnt(0) + s_barrier, so the in-flight loads
// complete under the 32 MFMAs + 8 ds_reads. Buffer parity fully unrolled
// (compile-time LDS bases).
// mode 0: z=0 -> Q bf16 (nh,s,d) pre-scaled by 0.125*log2e; z=1 -> K bf16 (nh,s,d);
//         z=2 -> V^T bf16 (nh,d,s) — all coalesced via LDS transpose
// mode 1: fp32 row-major (m,o) output
__global__ __launch_bounds__(256, 2) void gemm_bt(
    const u16* __restrict__ A,
    const u16* __restrict__ Wa, const u16* __restrict__ Wb, const u16* __restrict__ Wc,
    const float* __restrict__ ba, const float* __restrict__ bb, const float* __restrict__ bc,
    void* oa, void* ob_, void* oc, int mode)
{
    constexpr int K = 1024;
    __shared__ u16 smem[128 * 132];   // k-loop uses [0..16383] as 2x(At 4096 + Wt 4096)

    const int tid = threadIdx.x;
    const int lane = tid & 63, wv = tid >> 6;
    const int l15 = lane & 15, quad = lane >> 4;
    const int wr = wv >> 1, wc = wv & 1;

    // XCD-aware swizzle (grid is 8 x 64 x z; dispatch order = linear L)
    const int L = blockIdx.x + (blockIdx.y << 3) + (blockIdx.z << 9);
    const int g = L & 7;          // XCD (assumes round-robin dispatch)
    const int j = L >> 3;
    const int z = j >> 6;         // 0..2 (or 0)
    const int r = j & 63;
    const int m0 = ((g << 3) + (r & 7)) * 128;   // y-chunk per XCD
    const int n0 = (r >> 3) * 128;

    const u16* W = (z == 0) ? Wa : ((z == 1) ? Wb : Wc);
    const float* bs = (z == 0) ? ba : ((z == 1) ? bb : bc);
    void* out = (z == 0) ? oa : ((z == 1) ? ob_ : oc);
    const bool swap_ = (mode == 1) || (z < 2);   // swapped: tile row = o, col = m

    f32x4 acc[4][4];
#pragma unroll
    for (int i = 0; i < 4; ++i)
#pragma unroll
        for (int j2 = 0; j2 < 4; ++j2) acc[i][j2] = (f32x4)0.f;

    // staging geometry (per thread, k-invariant)
    const int c0 = (wv * 2) * 64 + lane;
    const int c1 = c0 + 64;
    const int row0 = c0 >> 2, row1 = c1 >> 2;
    const int ko0 = ((c0 & 3) ^ (row0 & 3)) * 8;   // XOR swizzle of k-chunks per row
    const int ko1 = ((c1 & 3) ^ (row1 & 3)) * 8;
    const u16* As0 = A + (size_t)(m0 + row0) * K + ko0;
    const u16* As1 = A + (size_t)(m0 + row1) * K + ko1;
    const u16* Ws0 = W + (size_t)(n0 + row0) * K + ko0;
    const u16* Ws1 = W + (size_t)(n0 + row1) * K + ko1;
    const int off0 = c0 * 8, off1 = c1 * 8;

    u16* const At0 = smem;         u16* const Wt0 = smem + 4096;
    u16* const At1 = smem + 8192;  u16* const Wt1 = smem + 12288;

    auto stage = [&](u16* Atb, u16* Wtb, int kk) {
        async16(As0 + kk, Atb + off0);
        async16(As1 + kk, Atb + off1);
        async16(Ws0 + kk, Wtb + off0);
        async16(Ws1 + kk, Wtb + off1);
    };
    auto compute = [&](const u16* Atb, const u16* Wtb) {
        bf16x8 af[4], wf[4];
#pragma unroll
        for (int t = 0; t < 4; ++t) {
            int rowa = wr * 64 + t * 16 + l15;
            af[t] = *(const bf16x8*)&Atb[rowa * 32 + ((quad ^ (rowa & 3)) * 8)];
            int rowb = wc * 64 + t * 16 + l15;
            wf[t] = *(const bf16x8*)&Wtb[rowb * 32 + ((quad ^ (rowb & 3)) * 8)];
        }
        if (swap_) {
#pragma unroll
            for (int rt = 0; rt < 4; ++rt)
#pragma unroll
                for (int ct = 0; ct < 4; ++ct)
                    acc[rt][ct] = __builtin_amdgcn_mfma_f32_16x16x32_bf16(wf[ct], af[rt], acc[rt][ct], 0, 0, 0);
        } else {
#pragma unroll
            for (int rt = 0; rt < 4; ++rt)
#pragma unroll
                for (int ct = 0; ct < 4; ++ct)
                    acc[rt][ct] = __builtin_amdgcn_mfma_f32_16x16x32_bf16(af[rt], wf[ct], acc[rt][ct], 0, 0, 0);
        }
    };

    // prologue: tile 0 -> buf0
    stage(At0, Wt0, 0);
    asm volatile("s_waitcnt vmcnt(0)" ::: "memory");
    __builtin_amdgcn_s_barrier();

#pragma unroll 1
    for (int kk = 0; kk < K - 64; kk += 64) {
        stage(At1, Wt1, kk + 32);
        compute(At0, Wt0);
        asm volatile("s_waitcnt vmcnt(0)" ::: "memory");
        __builtin_amdgcn_s_barrier();
        stage(At0, Wt0, kk + 64);
        compute(At1, Wt1);
        asm volatile("s_waitcnt vmcnt(0)" ::: "memory");
        __builtin_amdgcn_s_barrier();
    }
    // tiles 960 (in buf0) and 992
    stage(At1, Wt1, 992);
    compute(At0, Wt0);
    asm volatile("s_waitcnt vmcnt(0)" ::: "memory");
    __builtin_amdgcn_s_barrier();
    compute(At1, Wt1);

    if (mode == 1) {
        // swapped: row = o (quad*4+r), col = m (l15); pack float4 over o — coalesced fp32
#pragma unroll
        for (int rt = 0; rt < 4; ++rt)
#pragma unroll
            for (int ct = 0; ct < 4; ++ct) {
                int m_ = m0 + wr * 64 + rt * 16 + l15;
                int ob = n0 + wc * 64 + ct * 16 + quad * 4;
                float4 b4 = *(const float4*)&bs[ob];
                float4 v;
                v.x = acc[rt][ct][0] + b4.x;
                v.y = acc[rt][ct][1] + b4.y;
                v.z = acc[rt][ct][2] + b4.z;
                v.w = acc[rt][ct][3] + b4.w;
                *(float4*)((float*)out + (size_t)m_ * 1024 + ob) = v;
            }
        return;
    }

    __syncthreads();   // all waves done reading k-loop buffers before smem reuse

    const int n = m0 >> 11, s0 = m0 & 2047;
    if (z < 2) {
        // tile -> LDS T[m][o] (132 stride), then coalesced (nh,s,d) streams
        const float qs = (z == 0) ? 0.18033688011112042f : 1.0f;  // 0.125*log2(e)
#pragma unroll
        for (int rt = 0; rt < 4; ++rt)
#pragma unroll
            for (int ct = 0; ct < 4; ++ct) {
                int ml = wr * 64 + rt * 16 + l15;
                int ol = wc * 64 + ct * 16 + quad * 4;
                float4 b4 = *(const float4*)&bs[n0 + ol];
                float v0 = (acc[rt][ct][0] + b4.x) * qs;
                float v1 = (acc[rt][ct][1] + b4.y) * qs;
                float v2 = (acc[rt][ct][2] + b4.z) * qs;
                float v3 = (acc[rt][ct][3] + b4.w) * qs;
                u32x2 pv = { pack2bf(v0, v1), pack2bf(v2, v3) };
                *(u32x2*)&smem[ml * 132 + ol] = pv;
            }
        __syncthreads();
        const int h0 = n0 >> 6;
#pragma unroll
        for (int p = 0; p < 8; ++p) {
            int hh = p >> 2, qq = p & 3;
            int m = qq * 32 + (tid >> 3), d = (tid & 7) * 8;
            bf16x8 vv = *(const bf16x8*)&smem[m * 132 + hh * 64 + d];
            u16* dst = (u16*)out + ((size_t)((n * 16 + h0 + hh) * 2048 + s0 + m)) * 64 + d;
            *(bf16x8*)dst = vv;
        }
    } else {
        // V^T: tile -> LDS T[o][m], then coalesced (nh,d,s) rows
#pragma unroll
        for (int rt = 0; rt < 4; ++rt)
#pragma unroll
            for (int ct = 0; ct < 4; ++ct) {
                int ol = wc * 64 + ct * 16 + l15;
                int ml = wr * 64 + rt * 16 + quad * 4;
                float b = bs[n0 + ol];
                float v0 = acc[rt][ct][0] + b;
                float v1 = acc[rt][ct][1] + b;
                float v2 = acc[rt][ct][2] + b;
                float v3 = acc[rt][ct][3] + b;
                u32x2 pv = { pack2bf(v0, v1), pack2bf(v2, v3) };
                *(u32x2*)&smem[ol * 132 + ml] = pv;
            }
        __syncthreads();
#pragma unroll
        for (int p = 0; p < 8; ++p) {
            int o = p * 16 + (tid >> 4), ms = (tid & 15) * 8;
            bf16x8 vv = *(const bf16x8*)&smem[o * 132 + ms];
            int og = n0 + o;
            int h = og >> 6, d = og & 63;
            u16* dst = (u16*)out + ((size_t)((n * 16 + h) * 64 + d)) * 2048 + s0 + ms;
            *(bf16x8*)dst = vv;
        }
    }
}

// ---------------- flash attention ----------------
// Q bf16 (nh,s,d) PRE-SCALED by 0.125*log2e; K bf16 (nh,s,d); VT bf16 (nh,d,s).
// S^T = K.Q^T; fixed-max softmax (scores bounded: exp2 sums < 2^20, fp32-safe),
// per-lane lsum reduced once at the end. R3 version (verified 86.9us):
// QBLK=64 q per wave, in-register P redistribution via permlane swaps, mask
// bitmap precomputed, one barrier per K-tile.
// R4's 2-deep score pipeline REVERTED: it spilled (WRITE_SIZE 465MB of scratch
// traffic, VGPR capped at 128, 228us) — peak-live of two 64-reg score buffers
// exceeds the allocator budget at 2 waves/SIMD. Do not re-attempt without
// cutting the score tile in half.
__global__ __launch_bounds__(256, 2) void attn_kernel(
    const u16* __restrict__ Q, const u16* __restrict__ K_,
    const u16* __restrict__ VT, const int* __restrict__ mask,
    u16* __restrict__ Y)
{
    constexpr int S = 2048, DK = 64, STR = 72;
    __shared__ u16 Kt[2][64 * STR];
    __shared__ u16 Vt[2][64 * STR];

    const int tid = threadIdx.x;
    const int lane = tid & 63, w = tid >> 6;
    const int l15 = lane & 15, quad = lane >> 4;

    // Bijective XCD swizzle (512 blocks % 8 == 0): XCD g gets vb in
    // [g*64, g*64+64) = 8 whole heads -> K/V live-set per XCD ~= 4MB = one L2.
    const int L = blockIdx.x + (blockIdx.y << 3);
    const int vb = (L & 7) * 64 + (L >> 3);
    const int nh = vb >> 3;
    const int n = nh >> 4, h = nh & 15;
    const int qbase = (vb & 7) * 256;

    const u16* Qh = Q + (size_t)nh * S * DK;
    const u16* Kh = K_ + (size_t)nh * S * DK;
    const u16* Vh = VT + (size_t)nh * DK * S;   // row d, stride S

    bf16x8 qf[4][2];
#pragma unroll
    for (int nt = 0; nt < 4; ++nt)
#pragma unroll
        for (int st = 0; st < 2; ++st)
            qf[nt][st] = *(const bf16x8*)(Qh + (size_t)(qbase + w * 64 + nt * 16 + l15) * DK + st * 32 + quad * 8);

    f32x4 o[4][4];   // [dt][nt]
#pragma unroll
    for (int dt = 0; dt < 4; ++dt)
#pragma unroll
        for (int nt = 0; nt < 4; ++nt) o[dt][nt] = (f32x4)0.f;
    float lsum[4] = {0.f, 0.f, 0.f, 0.f};

    const int r0 = tid >> 3, c8 = (tid & 7) * 8;

    // per-tile "fully unmasked" bitmap (one ballot per tile, once)
    u32 bm = 0;
    for (int t = 0; t < 32; ++t) {
        int mv = mask[n * S + t * 64 + lane];
        if (__ballot(mv != 0) == ~0ull) bm |= (1u << t);
    }

    // prologue: tile 0 -> buf 0
    {
        bf16x8 k0 = *(const bf16x8*)(Kh + (size_t)r0 * 64 + c8);
        bf16x8 k1 = *(const bf16x8*)(Kh + (size_t)(r0 + 32) * 64 + c8);
        bf16x8 v0 = *(const bf16x8*)(Vh + (size_t)r0 * S + c8);
        bf16x8 v1 = *(const bf16x8*)(Vh + (size_t)(r0 + 32) * S + c8);
        *(bf16x8*)&Kt[0][r0 * STR + c8] = k0;
        *(bf16x8*)&Kt[0][(r0 + 32) * STR + c8] = k1;
        *(bf16x8*)&Vt[0][r0 * STR + c8] = v0;
        *(bf16x8*)&Vt[0][(r0 + 32) * STR + c8] = v1;
    }
    __syncthreads();

    const f32x4 zf = (f32x4)0.f;

    for (int it = 0; it < 32; ++it) {
        const int cur = it & 1, nxt = cur ^ 1;
        const u16* Ktc = &Kt[cur][0];
        const u16* Vtc = &Vt[cur][0];

        // prefetch next tile into registers (latency hides under QK+softmax)
        const int kkn = ((it + 1) << 6) & (S - 1);
        bf16x8 rk0 = *(const bf16x8*)(Kh + (size_t)(kkn + r0) * 64 + c8);
        bf16x8 rk1 = *(const bf16x8*)(Kh + (size_t)(kkn + r0 + 32) * 64 + c8);
        bf16x8 rv0 = *(const bf16x8*)(Vh + (size_t)r0 * S + kkn + c8);
        bf16x8 rv1 = *(const bf16x8*)(Vh + (size_t)(r0 + 32) * S + kkn + c8);

        // ---- S^T = K.Q^T ---- (st=0 uses zero C: no sacc zero-init)
        f32x4 sacc[4][4];   // [jt][nt]
        __builtin_amdgcn_s_setprio(1);
#pragma unroll
        for (int jt = 0; jt < 4; ++jt) {
            bf16x8 kf = *(const bf16x8*)&Ktc[(jt * 16 + l15) * STR + quad * 8];
#pragma unroll
            for (int nt = 0; nt < 4; ++nt)
                sacc[jt][nt] = __builtin_amdgcn_mfma_f32_16x16x32_bf16(kf, qf[nt][0], zf, 0, 0, 0);
        }
#pragma unroll
        for (int jt = 0; jt < 4; ++jt) {
            bf16x8 kf = *(const bf16x8*)&Ktc[(jt * 16 + l15) * STR + 32 + quad * 8];
#pragma unroll
            for (int nt = 0; nt < 4; ++nt)
                sacc[jt][nt] = __builtin_amdgcn_mfma_f32_16x16x32_bf16(kf, qf[nt][1], sacc[jt][nt], 0, 0, 0);
        }
        __builtin_amdgcn_s_setprio(0);

        if (!((bm >> it) & 1)) {   // rare: tile has masked keys
#pragma unroll
            for (int jt = 0; jt < 4; ++jt)
#pragma unroll
                for (int r = 0; r < 4; ++r) {
                    int mv = mask[n * S + it * 64 + jt * 16 + quad * 4 + r];
#pragma unroll
                    for (int nt = 0; nt < 4; ++nt)
                        if (mv == 0) sacc[jt][nt][r] = -1e30f;
                }
        }

        // ---- softmax (fixed max, exp2 domain) + in-register P redistribution ----
        bf16x8 pb[4][2];   // [nt][kt]
#pragma unroll
        for (int nt = 0; nt < 4; ++nt) {
            float ps = 0.f;
            u32 pkx[4], pky[4];
#pragma unroll
            for (int jt = 0; jt < 4; ++jt) {
                float e0 = __builtin_amdgcn_exp2f(sacc[jt][nt][0]);
                float e1 = __builtin_amdgcn_exp2f(sacc[jt][nt][1]);
                float e2 = __builtin_amdgcn_exp2f(sacc[jt][nt][2]);
                float e3 = __builtin_amdgcn_exp2f(sacc[jt][nt][3]);
                ps += (e0 + e1) + (e2 + e3);
                pkx[jt] = cvtpk(e0, e1);   // k = 16jt+4sq+{0,1}
                pky[jt] = cvtpk(e2, e3);   // k = 16jt+4sq+{2,3}
            }
            lsum[nt] += ps;
#pragma unroll
            for (int kt = 0; kt < 2; ++kt) {
                // step1: 32-swap -> A1=[A.q0,A.q1,B.q0,B.q1], B1=[A.q2,A.q3,B.q2,B.q3]
                auto rX = __builtin_amdgcn_permlane32_swap(pkx[2 * kt], pkx[2 * kt + 1], false, false);
                auto rY = __builtin_amdgcn_permlane32_swap(pky[2 * kt], pky[2 * kt + 1], false, false);
                // step2: 16-swap -> out0=[A.q0,A.q2,B.q0,B.q2], out1=[A.q1,A.q3,B.q1,B.q3]
                auto sX = __builtin_amdgcn_permlane16_swap(rX[0], rX[1], false, false);
                auto sY = __builtin_amdgcn_permlane16_swap(rY[0], rY[1], false, false);
                union { u32 u[4]; bf16x8 v; } pu;
                pu.u[0] = sX[0];   // k = 32kt+8qd+{0,1}
                pu.u[1] = sY[0];   // +{2,3}
                pu.u[2] = sX[1];   // +{4,5}
                pu.u[3] = sY[1];   // +{6,7}
                pb[nt][kt] = pu.v;
            }
        }

        // ---- stage next tile into buf[nxt] (ds_write drains under PV) ----
        *(bf16x8*)&Kt[nxt][r0 * STR + c8] = rk0;
        *(bf16x8*)&Kt[nxt][(r0 + 32) * STR + c8] = rk1;
        *(bf16x8*)&Vt[nxt][r0 * STR + c8] = rv0;
        *(bf16x8*)&Vt[nxt][(r0 + 32) * STR + c8] = rv1;

        // ---- O^T += V^T . P^T  (P entirely in registers) ----
        __builtin_amdgcn_s_setprio(1);
#pragma unroll
        for (int kt = 0; kt < 2; ++kt) {
#pragma unroll
            for (int dt = 0; dt < 4; ++dt) {
                bf16x8 vf = *(const bf16x8*)&Vtc[(dt * 16 + l15) * STR + kt * 32 + quad * 8];
#pragma unroll
                for (int nt = 0; nt < 4; ++nt)
                    o[dt][nt] = __builtin_amdgcn_mfma_f32_16x16x32_bf16(vf, pb[nt][kt], o[dt][nt], 0, 0, 0);
            }
        }
        __builtin_amdgcn_s_setprio(0);

        __syncthreads();   // buf[nxt] published; everyone done reading buf[cur]
    }

    // ---- epilogue ----
#pragma unroll
    for (int nt = 0; nt < 4; ++nt) {
        float ls = lsum[nt];
        ls += __shfl_xor(ls, 16);
        ls += __shfl_xor(ls, 32);
        float rl = (ls > 0.f) ? 1.f / ls : 0.f;
        int qi = qbase + w * 64 + nt * 16 + l15;
#pragma unroll
        for (int dt = 0; dt < 4; ++dt) {
            u32x2 pv = { pack2bf(o[dt][nt][0] * rl, o[dt][nt][1] * rl),
                         pack2bf(o[dt][nt][2] * rl, o[dt][nt][3] * rl) };
            size_t base = ((size_t)(n * 2048 + qi)) * 1024 + h * 64 + dt * 16 + quad * 4;
            *(u32x2*)(Y + base) = pv;
        }
    }
}

// ---------------- host ----------------
extern "C" void kernel_launch(void* const* d_in, const int* in_sizes, int n_in,
                              void* d_out, int out_size, void* d_ws, size_t ws_size,
                              hipStream_t stream) {
    const float* x  = (const float*)d_in[0];
    const int* mask = (const int*)d_in[1];
    const float* Wq = (const float*)d_in[2];
    const float* bq = (const float*)d_in[3];
    const float* Wk = (const float*)d_in[4];
    const float* bk = (const float*)d_in[5];
    const float* Wv = (const float*)d_in[6];
    const float* bv = (const float*)d_in[7];
    const float* Wp = (const float*)d_in[8];
    const float* bp = (const float*)d_in[9];

    char* ws = (char*)d_ws;
    u16* xb  = (u16*)(ws);
    u16* wqb = (u16*)(ws + (16u << 20));
    u16* wkb = (u16*)(ws + (18u << 20));
    u16* wvb = (u16*)(ws + (20u << 20));
    u16* wpb = (u16*)(ws + (22u << 20));
    u16* Qb  = (u16*)(ws + (24u << 20));
    u16* Kb  = (u16*)(ws + (40u << 20));
    u16* Vb  = (u16*)(ws + (56u << 20));   // V^T (nh, d, s)
    u16* Yb  = (u16*)(ws + (72u << 20));

    cvt_kernel<<<4096, 256, 0, stream>>>(x, xb, 8388608);
    cvt4_kernel<<<dim3(512, 4), 256, 0, stream>>>(Wq, Wk, Wv, Wp, wqb, wkb, wvb, wpb);

    gemm_bt<<<dim3(8, 64, 3), 256, 0, stream>>>(xb, wqb, wkb, wvb, bq, bk, bv,
                                                (void*)Qb, (void*)Kb, (void*)Vb, 0);

    attn_kernel<<<dim3(8, 64), 256, 0, stream>>>(Qb, Kb, Vb, mask, Yb);

    gemm_bt<<<dim3(8, 64, 1), 256, 0, stream>>>(Yb, wpb, wpb, wpb, bp, bp, bp,
                                                d_out, d_out, d_out, 1);
}